// Round 2
// baseline (24183.434 us; speedup 1.0000x reference)
//
#include <hip/hip_runtime.h>

typedef unsigned short u16;
typedef short bf16x8 __attribute__((ext_vector_type(8)));
typedef float f32x4 __attribute__((ext_vector_type(4)));

#define B_ 256
#define T_ 512
#define I_ 64
#define H_ 512

// ---------------- ws layout (bytes) ----------------
#define OFF_CTR   0u           // 16 x u32 (ctr0[8], ctr1[8])
#define OFF_B0    256u         // 2048 f32
#define OFF_B1    8448u        // 2048 f32
#define OFF_WIH0  16640u       // 2048x64 bf16
#define OFF_WHH0  278784u      // 2048x512 bf16
#define OFF_WIH1  2375936u     // 2048x512 bf16
#define OFF_WHH1  4473088u     // 2048x512 bf16
#define OFF_HX    6570240u     // 2 x 256 x 512 bf16
#define OFF_H2L   7094528u     // 256x512 f32
#define OFF_H1    7618816u     // 512x256x512 bf16
#define WS_NEEDED 141836544u

static __device__ __forceinline__ u16 f2b(float f) {
  union { float f; unsigned u; } v; v.f = f;
  unsigned r = (v.u + 0x7FFFu + ((v.u >> 16) & 1u)) >> 16;
  return (u16)r;
}
static __device__ __forceinline__ float sigm(float x) { return 1.f / (1.f + __expf(-x)); }
static __device__ __forceinline__ float tanh_(float x) { return 1.f - 2.f / (__expf(2.f * x) + 1.f); }

// ---------------- prep: bf16 weight conversion, bias sums, barrier counters ----------------
__global__ void prep_kernel(const float* __restrict__ Wih0, const float* __restrict__ Whh0,
                            const float* __restrict__ bih0, const float* __restrict__ bhh0,
                            const float* __restrict__ Wih1, const float* __restrict__ Whh1,
                            const float* __restrict__ bih1, const float* __restrict__ bhh1,
                            char* __restrict__ ws) {
  unsigned* ctr = (unsigned*)(ws + OFF_CTR);
  float* b0 = (float*)(ws + OFF_B0);
  float* b1 = (float*)(ws + OFF_B1);
  u16* wih0b = (u16*)(ws + OFF_WIH0);
  u16* whh0b = (u16*)(ws + OFF_WHH0);
  u16* wih1b = (u16*)(ws + OFF_WIH1);
  u16* whh1b = (u16*)(ws + OFF_WHH1);

  long long i = (long long)blockIdx.x * 256 + threadIdx.x;
  if (i < 16) { ctr[i] = 0u; return; }
  i -= 16;
  if (i < 2048) { b0[i] = bih0[i] + bhh0[i]; return; }
  i -= 2048;
  if (i < 2048) { b1[i] = bih1[i] + bhh1[i]; return; }
  i -= 2048;
  if (i < 131072) { wih0b[i] = f2b(Wih0[i]); return; }
  i -= 131072;
  if (i < 1048576) { whh0b[i] = f2b(Whh0[i]); return; }
  i -= 1048576;
  if (i < 1048576) { wih1b[i] = f2b(Wih1[i]); return; }
  i -= 1048576;
  if (i < 1048576) { whh1b[i] = f2b(Whh1[i]); return; }
}

// ---------------- persistent LSTM layer ----------------
// grid = 256 blocks: jn = blockIdx&31 (hidden chunk of 16), ib = blockIdx>>5 (batch chunk of 32)
// block = 256 threads = 4 waves; waves K-split the gate GEMM; partials reduced via LDS.
template <bool IS_L0>
__global__ __launch_bounds__(256, 1) void lstm_layer(
    const float* __restrict__ x,      // L0: [B,T,64]
    const u16* __restrict__ Wib,      // bf16: L0 [2048][64], L1 [2048][512]
    const u16* __restrict__ Whb,      // bf16 [2048][512]
    const float* __restrict__ bias,   // [2048] (bih+bhh)
    u16* __restrict__ hx,             // [2][256][512] bf16 exchange
    const u16* __restrict__ h1in,     // L1: [512][256][512] bf16
    u16* __restrict__ h1out,          // L0: [512][256][512] bf16
    float* __restrict__ h2last,       // L1: [256][512] f32
    unsigned* __restrict__ ctr)       // [8] group barrier counters
{
  __shared__ __align__(16) u16 Wh_s[64 * 520];          // Whh slice, row stride 520 (bank-safe)
  __shared__ __align__(16) u16 Ah_s[32 * 520];          // h_prev staging
  __shared__ __align__(16) float Gp_s[4 * 32 * 68];     // per-wave gate partials
  __shared__ __align__(16) u16 Wx_s[IS_L0 ? 64 * 72 : 8];
  __shared__ __align__(16) u16 Ax_s[IS_L0 ? 32 * 72 : 8];

  const int tid = threadIdx.x;
  const int wv = tid >> 6;
  const int lane = tid & 63;
  const int quad = lane >> 4;
  const int l15 = lane & 15;
  const int jn = blockIdx.x & 31;
  const int ib = blockIdx.x >> 5;

  // one-time: stage Whh slice (local row n = g*16+hl -> global row g*512 + jn*16 + hl)
  // 64 rows x 512 u16 -> 64x64 uint4 stores  (BUG FIX: was 64*32 / c&31, left half of
  // each row uninitialized -> NaN bf16 patterns entered the MFMA B-fragments)
  for (int i = tid; i < 64 * 64; i += 256) {
    int lr = i >> 6, c = i & 63;
    int gr = (lr >> 4) * 512 + jn * 16 + (lr & 15);
    *(uint4*)&Wh_s[lr * 520 + c * 8] = *(const uint4*)&Whb[(size_t)gr * 512 + c * 8];
  }
  if constexpr (IS_L0) {
    for (int i = tid; i < 64 * 8; i += 256) {
      int lr = i >> 3, c = i & 7;
      int gr = (lr >> 4) * 512 + jn * 16 + (lr & 15);
      *(uint4*)&Wx_s[lr * 72 + c * 8] = *(const uint4*)&Wib[(size_t)gr * 64 + c * 8];
    }
  }

  float bias_r[4];
#pragma unroll
  for (int g = 0; g < 4; ++g) bias_r[g] = bias[g * 512 + jn * 16 + (tid & 15)];

  float cst[2] = {0.f, 0.f};  // cell state: (b = tid>>4 + 16p, hl = tid&15)

  int kbeg, kend;
  if constexpr (IS_L0) {  // 18 ksteps: 0-1 input (K=64), 2-17 recurrent (K=512)
    kbeg = (wv <= 1) ? 5 * wv : 10 + 4 * (wv - 2);
    kend = kbeg + ((wv <= 1) ? 5 : 4);
  } else {                // 32 ksteps: 0-15 input (K=512, global), 16-31 recurrent (LDS)
    kbeg = 8 * wv;
    kend = kbeg + 8;
  }

  const f32x4 zf = {0.f, 0.f, 0.f, 0.f};

  for (int t = 0; t < T_; ++t) {
    // ---- stage A ----
    if constexpr (IS_L0) {
      int row = tid >> 3, cc = (tid & 7) * 8;
      const float* xp = x + ((size_t)(ib * 32 + row) * T_ + t) * 64 + cc;
      float4 a = *(const float4*)xp;
      float4 b = *(const float4*)(xp + 4);
      uint4 v;
      v.x = (unsigned)f2b(a.x) | ((unsigned)f2b(a.y) << 16);
      v.y = (unsigned)f2b(a.z) | ((unsigned)f2b(a.w) << 16);
      v.z = (unsigned)f2b(b.x) | ((unsigned)f2b(b.y) << 16);
      v.w = (unsigned)f2b(b.z) | ((unsigned)f2b(b.w) << 16);
      *(uint4*)&Ax_s[row * 72 + cc] = v;
    }
    {
      const u16* hr = hx + (size_t)(t & 1) * (B_ * H_);
      for (int i = tid; i < 2048; i += 256) {
        int row = i >> 6, c = i & 63;
        uint4 v;
        if (t == 0) { v.x = 0u; v.y = 0u; v.z = 0u; v.w = 0u; }
        else v = *(const uint4*)&hr[(ib * 32 + row) * 512 + c * 8];
        *(uint4*)&Ah_s[row * 520 + c * 8] = v;
      }
    }
    __syncthreads();

    // ---- K loop (this wave's k range, all 2x4 tiles) ----
    f32x4 acc[2][4];
#pragma unroll
    for (int mt = 0; mt < 2; ++mt)
#pragma unroll
      for (int nt = 0; nt < 4; ++nt) acc[mt][nt] = zf;

    for (int ks = kbeg; ks < kend; ++ks) {
      bf16x8 af[2], bf[4];
      if constexpr (IS_L0) {
        if (ks < 2) {
          int kk = ks * 32 + quad * 8;
          af[0] = *(const bf16x8*)&Ax_s[l15 * 72 + kk];
          af[1] = *(const bf16x8*)&Ax_s[(16 + l15) * 72 + kk];
#pragma unroll
          for (int nt = 0; nt < 4; ++nt) bf[nt] = *(const bf16x8*)&Wx_s[(nt * 16 + l15) * 72 + kk];
        } else {
          int kk = (ks - 2) * 32 + quad * 8;
          af[0] = *(const bf16x8*)&Ah_s[l15 * 520 + kk];
          af[1] = *(const bf16x8*)&Ah_s[(16 + l15) * 520 + kk];
#pragma unroll
          for (int nt = 0; nt < 4; ++nt) bf[nt] = *(const bf16x8*)&Wh_s[(nt * 16 + l15) * 520 + kk];
        }
      } else {
        if (ks < 16) {
          int kk = ks * 32 + quad * 8;
          const u16* hbase = h1in + (size_t)t * (B_ * H_);
          af[0] = *(const bf16x8*)&hbase[(ib * 32 + l15) * 512 + kk];
          af[1] = *(const bf16x8*)&hbase[(ib * 32 + 16 + l15) * 512 + kk];
#pragma unroll
          for (int nt = 0; nt < 4; ++nt)
            bf[nt] = *(const bf16x8*)&Wib[(size_t)(nt * 512 + jn * 16 + l15) * 512 + kk];
        } else {
          int kk = (ks - 16) * 32 + quad * 8;
          af[0] = *(const bf16x8*)&Ah_s[l15 * 520 + kk];
          af[1] = *(const bf16x8*)&Ah_s[(16 + l15) * 520 + kk];
#pragma unroll
          for (int nt = 0; nt < 4; ++nt) bf[nt] = *(const bf16x8*)&Wh_s[(nt * 16 + l15) * 520 + kk];
        }
      }
#pragma unroll
      for (int mt = 0; mt < 2; ++mt)
#pragma unroll
        for (int nt = 0; nt < 4; ++nt)
          acc[mt][nt] = __builtin_amdgcn_mfma_f32_16x16x32_bf16(af[mt], bf[nt], acc[mt][nt], 0, 0, 0);
    }

    // ---- dump per-wave partials (D: col=lane&15, row=quad*4+reg) ----
#pragma unroll
    for (int mt = 0; mt < 2; ++mt)
#pragma unroll
      for (int nt = 0; nt < 4; ++nt)
#pragma unroll
        for (int r = 0; r < 4; ++r)
          Gp_s[(wv * 32 + mt * 16 + quad * 4 + r) * 68 + nt * 16 + l15] = acc[mt][nt][r];
    __syncthreads();

    // ---- elementwise: reduce partials, gates, cell/h update ----
    u16* hw = hx + (size_t)((t + 1) & 1) * (B_ * H_);
#pragma unroll
    for (int p = 0; p < 2; ++p) {
      int b = (tid >> 4) + p * 16;
      int hl = tid & 15;
      float pre[4];
#pragma unroll
      for (int g = 0; g < 4; ++g) {
        int c = g * 16 + hl;
        pre[g] = bias_r[g]
               + Gp_s[(0 * 32 + b) * 68 + c] + Gp_s[(1 * 32 + b) * 68 + c]
               + Gp_s[(2 * 32 + b) * 68 + c] + Gp_s[(3 * 32 + b) * 68 + c];
      }
      float iv = sigm(pre[0]);
      float fv = sigm(pre[1]);
      float gv = tanh_(pre[2]);
      float ov = sigm(pre[3]);
      float cn = fv * cst[p] + iv * gv;
      cst[p] = cn;
      float hv = ov * tanh_(cn);
      int bg = ib * 32 + b, hg = jn * 16 + hl;
      u16 hb = f2b(hv);
      hw[bg * 512 + hg] = hb;
      if constexpr (IS_L0) {
        h1out[(size_t)t * (B_ * H_) + bg * 512 + hg] = hb;
      } else {
        if (t == T_ - 1) h2last[bg * 512 + hg] = hv;
      }
    }
    __syncthreads();

    // ---- per-group barrier (32 blocks sharing batch chunk ib) ----
    if (tid == 0) {
      __threadfence();  // release h writes (agent scope)
      __hip_atomic_fetch_add(ctr + ib, 1u, __ATOMIC_RELAXED, __HIP_MEMORY_SCOPE_AGENT);
      unsigned tgt = 32u * (unsigned)(t + 1);
      while (__hip_atomic_load(ctr + ib, __ATOMIC_RELAXED, __HIP_MEMORY_SCOPE_AGENT) < tgt)
        __builtin_amdgcn_s_sleep(1);
      __threadfence();  // acquire remote h writes
    }
    __syncthreads();
  }
}

// ---------------- final FC: out[b] = h2last[b,:] . Wfc + bfc ----------------
__global__ void fc_kernel(const float* __restrict__ h2, const float* __restrict__ Wfc,
                          const float* __restrict__ bfc, float* __restrict__ out) {
  int b = blockIdx.x, l = threadIdx.x;  // 64 threads
  float s = 0.f;
#pragma unroll
  for (int j = 0; j < 8; ++j) s += h2[b * 512 + l + j * 64] * Wfc[l + j * 64];
#pragma unroll
  for (int off = 32; off; off >>= 1) s += __shfl_down(s, off);
  if (l == 0) out[b] = s + bfc[0];
}

extern "C" void kernel_launch(void* const* d_in, const int* in_sizes, int n_in,
                              void* d_out, int out_size, void* d_ws, size_t ws_size,
                              hipStream_t stream) {
  if (ws_size < (size_t)WS_NEEDED) return;  // need ~135.3 MB scratch

  const float* x    = (const float*)d_in[0];
  const float* Wih0 = (const float*)d_in[1];
  const float* Whh0 = (const float*)d_in[2];
  const float* bih0 = (const float*)d_in[3];
  const float* bhh0 = (const float*)d_in[4];
  const float* Wih1 = (const float*)d_in[5];
  const float* Whh1 = (const float*)d_in[6];
  const float* bih1 = (const float*)d_in[7];
  const float* bhh1 = (const float*)d_in[8];
  const float* Wfc  = (const float*)d_in[9];
  const float* bfc  = (const float*)d_in[10];

  char* ws = (char*)d_ws;
  unsigned* ctr  = (unsigned*)(ws + OFF_CTR);
  float* b0      = (float*)(ws + OFF_B0);
  float* b1      = (float*)(ws + OFF_B1);
  u16* wih0b     = (u16*)(ws + OFF_WIH0);
  u16* whh0b     = (u16*)(ws + OFF_WHH0);
  u16* wih1b     = (u16*)(ws + OFF_WIH1);
  u16* whh1b     = (u16*)(ws + OFF_WHH1);
  u16* hx        = (u16*)(ws + OFF_HX);
  float* h2l     = (float*)(ws + OFF_H2L);
  u16* h1ws      = (u16*)(ws + OFF_H1);
  float* out     = (float*)d_out;

  // prep: 16 + 2048*2 + 131072 + 3*1048576 = 3,280,912 elements
  prep_kernel<<<12817, 256, 0, stream>>>(Wih0, Whh0, bih0, bhh0, Wih1, Whh1, bih1, bhh1, ws);

  lstm_layer<true><<<256, 256, 0, stream>>>(x, wih0b, whh0b, b0, hx, (const u16*)nullptr,
                                            h1ws, (float*)nullptr, ctr);
  lstm_layer<false><<<256, 256, 0, stream>>>((const float*)nullptr, wih1b, whh1b, b1, hx, h1ws,
                                             (u16*)nullptr, h2l, ctr + 8);
  fc_kernel<<<256, 64, 0, stream>>>(h2l, Wfc, bfc, out);
}

// Round 3
// 8895.870 us; speedup vs baseline: 2.7185x; 2.7185x over previous
//
#include <hip/hip_runtime.h>

typedef unsigned short u16;
typedef unsigned long long u64;
typedef short bf16x8 __attribute__((ext_vector_type(8)));
typedef float f32x4 __attribute__((ext_vector_type(4)));

#define B_ 256
#define T_ 512
#define I_ 64
#define H_ 512

// ---------------- ws layout (bytes) ----------------
#define OFF_FLAGS 0u           // 512 x u32 (layer0: [0..255], layer1: [256..511])
#define OFF_B0    2048u        // 2048 f32
#define OFF_B1    10240u       // 2048 f32
#define OFF_WIH0  18432u       // 2048x64 bf16
#define OFF_WHH0  280576u      // 2048x512 bf16
#define OFF_WIH1  2377728u     // 2048x512 bf16
#define OFF_WHH1  4474880u     // 2048x512 bf16
#define OFF_HX    6572032u     // 2 x 256 x 512 bf16
#define OFF_H2L   7096320u     // 256x512 f32
#define OFF_H1    7620608u     // 512x256x512 bf16
#define WS_NEEDED 141838336u

#define AQ __ATOMIC_RELAXED
#define SC __HIP_MEMORY_SCOPE_AGENT

static __device__ __forceinline__ u16 f2b(float f) {
  union { float f; unsigned u; } v; v.f = f;
  unsigned r = (v.u + 0x7FFFu + ((v.u >> 16) & 1u)) >> 16;
  return (u16)r;
}
static __device__ __forceinline__ float sigm(float x) { return 1.f / (1.f + __expf(-x)); }
static __device__ __forceinline__ float tanh_(float x) { return 1.f - 2.f / (__expf(2.f * x) + 1.f); }

// ---------------- prep: bf16 weight conversion, bias sums, flag reset ----------------
__global__ void prep_kernel(const float* __restrict__ Wih0, const float* __restrict__ Whh0,
                            const float* __restrict__ bih0, const float* __restrict__ bhh0,
                            const float* __restrict__ Wih1, const float* __restrict__ Whh1,
                            const float* __restrict__ bih1, const float* __restrict__ bhh1,
                            char* __restrict__ ws) {
  unsigned* flags = (unsigned*)(ws + OFF_FLAGS);
  float* b0 = (float*)(ws + OFF_B0);
  float* b1 = (float*)(ws + OFF_B1);
  u16* wih0b = (u16*)(ws + OFF_WIH0);
  u16* whh0b = (u16*)(ws + OFF_WHH0);
  u16* wih1b = (u16*)(ws + OFF_WIH1);
  u16* whh1b = (u16*)(ws + OFF_WHH1);

  long long i = (long long)blockIdx.x * 256 + threadIdx.x;
  if (i < 512) { __hip_atomic_store(&flags[i], 0u, AQ, SC); return; }
  i -= 512;
  if (i < 2048) { b0[i] = bih0[i] + bhh0[i]; return; }
  i -= 2048;
  if (i < 2048) { b1[i] = bih1[i] + bhh1[i]; return; }
  i -= 2048;
  if (i < 131072) { wih0b[i] = f2b(Wih0[i]); return; }
  i -= 131072;
  if (i < 1048576) { whh0b[i] = f2b(Whh0[i]); return; }
  i -= 1048576;
  if (i < 1048576) { wih1b[i] = f2b(Wih1[i]); return; }
  i -= 1048576;
  if (i < 1048576) { whh1b[i] = f2b(Whh1[i]); return; }
}

// ---------------- persistent LSTM layer ----------------
// grid = 256 blocks: jn = blockIdx&31 (hidden chunk of 16), ib = blockIdx>>5 (batch chunk of 32)
// block = 256 threads = 4 waves; waves K-split the gate GEMM; partials reduced via LDS.
// Cross-block h exchange: write-through agent-scope relaxed atomics + per-block flags.
// No __threadfence (agent fences force L2 wb/inv each step — that was the 24 us/step cost).
template <bool IS_L0>
__global__ __launch_bounds__(256, 1) void lstm_layer(
    const float* __restrict__ x,      // L0: [B,T,64]
    const u16* __restrict__ Wib,      // bf16: L0 [2048][64], L1 [2048][512]
    const u16* __restrict__ Whb,      // bf16 [2048][512]
    const float* __restrict__ bias,   // [2048] (bih+bhh)
    unsigned* __restrict__ hx32,      // [2][256][512] bf16 exchange, viewed as u32
    const u16* __restrict__ h1in,     // L1: [512][256][512] bf16
    unsigned* __restrict__ h1out32,   // L0: [512][256][512] bf16, viewed as u32
    float* __restrict__ h2last,       // L1: [256][512] f32
    unsigned* __restrict__ flags)     // [256] per-block step flags
{
  __shared__ __align__(16) u16 Wh_s[64 * 520];          // Whh slice, row stride 520
  __shared__ __align__(16) u16 Ah_s[32 * 520];          // h_prev staging
  __shared__ __align__(16) float Gp_s[4 * 32 * 68];     // per-wave gate partials
  __shared__ __align__(16) u16 Wx_s[IS_L0 ? 64 * 72 : 8];
  __shared__ __align__(16) u16 Ax_s[IS_L0 ? 32 * 72 : 8];

  const int tid = threadIdx.x;
  const int wv = tid >> 6;
  const int lane = tid & 63;
  const int quad = lane >> 4;
  const int l15 = lane & 15;
  const int jn = blockIdx.x & 31;
  const int ib = blockIdx.x >> 5;

  // one-time: stage Whh slice (local row n = g*16+hl -> global row g*512 + jn*16 + hl)
  for (int i = tid; i < 64 * 64; i += 256) {
    int lr = i >> 6, c = i & 63;
    int gr = (lr >> 4) * 512 + jn * 16 + (lr & 15);
    *(uint4*)&Wh_s[lr * 520 + c * 8] = *(const uint4*)&Whb[(size_t)gr * 512 + c * 8];
  }
  if constexpr (IS_L0) {
    for (int i = tid; i < 64 * 8; i += 256) {
      int lr = i >> 3, c = i & 7;
      int gr = (lr >> 4) * 512 + jn * 16 + (lr & 15);
      *(uint4*)&Wx_s[lr * 72 + c * 8] = *(const uint4*)&Wib[(size_t)gr * 64 + c * 8];
    }
  }

  // elementwise mapping: erow = batch row 0..31, ecp = col pair 0..7 (cols 2ecp, 2ecp+1)
  const int erow = tid >> 3;
  const int ecp = tid & 7;
  float bias2[4][2];
#pragma unroll
  for (int g = 0; g < 4; ++g) {
    bias2[g][0] = bias[g * 512 + jn * 16 + 2 * ecp];
    bias2[g][1] = bias[g * 512 + jn * 16 + 2 * ecp + 1];
  }
  float cst2[2] = {0.f, 0.f};  // cell state for (erow, 2ecp) and (erow, 2ecp+1)

  int kbeg, kend;
  if constexpr (IS_L0) {  // 18 ksteps: 0-1 input (K=64), 2-17 recurrent (K=512)
    kbeg = (wv <= 1) ? 5 * wv : 10 + 4 * (wv - 2);
    kend = kbeg + ((wv <= 1) ? 5 : 4);
  } else {                // 32 ksteps: 0-15 input (K=512, global), 16-31 recurrent (LDS)
    kbeg = 8 * wv;
    kend = kbeg + 8;
  }

  const f32x4 zf = {0.f, 0.f, 0.f, 0.f};

  for (int t = 0; t < T_; ++t) {
    // ---- stage A ----
    if constexpr (IS_L0) {
      int row = tid >> 3, cc = (tid & 7) * 8;
      const float* xp = x + ((size_t)(ib * 32 + row) * T_ + t) * 64 + cc;
      float4 a = *(const float4*)xp;
      float4 b = *(const float4*)(xp + 4);
      uint4 v;
      v.x = (unsigned)f2b(a.x) | ((unsigned)f2b(a.y) << 16);
      v.y = (unsigned)f2b(a.z) | ((unsigned)f2b(a.w) << 16);
      v.z = (unsigned)f2b(b.x) | ((unsigned)f2b(b.y) << 16);
      v.w = (unsigned)f2b(b.z) | ((unsigned)f2b(b.w) << 16);
      *(uint4*)&Ax_s[row * 72 + cc] = v;
    }
    {
      // h_prev: agent-scope u64 atomic loads (bypass stale L1/L2 copies)
      u64* hr64 = (u64*)hx32 + (size_t)(t & 1) * (B_ * H_ / 4);
      for (int i = tid; i < 4096; i += 256) {
        int row = i >> 7, c64 = i & 127;
        u64 v = 0ull;
        if (t) v = __hip_atomic_load(&hr64[(ib * 32 + row) * 128 + c64], AQ, SC);
        *(u64*)&Ah_s[row * 520 + c64 * 4] = v;
      }
    }
    __syncthreads();

    // ---- K loop (this wave's k range, all 2x4 tiles) ----
    f32x4 acc[2][4];
#pragma unroll
    for (int mt = 0; mt < 2; ++mt)
#pragma unroll
      for (int nt = 0; nt < 4; ++nt) acc[mt][nt] = zf;

    for (int ks = kbeg; ks < kend; ++ks) {
      bf16x8 af[2], bf[4];
      if constexpr (IS_L0) {
        if (ks < 2) {
          int kk = ks * 32 + quad * 8;
          af[0] = *(const bf16x8*)&Ax_s[l15 * 72 + kk];
          af[1] = *(const bf16x8*)&Ax_s[(16 + l15) * 72 + kk];
#pragma unroll
          for (int nt = 0; nt < 4; ++nt) bf[nt] = *(const bf16x8*)&Wx_s[(nt * 16 + l15) * 72 + kk];
        } else {
          int kk = (ks - 2) * 32 + quad * 8;
          af[0] = *(const bf16x8*)&Ah_s[l15 * 520 + kk];
          af[1] = *(const bf16x8*)&Ah_s[(16 + l15) * 520 + kk];
#pragma unroll
          for (int nt = 0; nt < 4; ++nt) bf[nt] = *(const bf16x8*)&Wh_s[(nt * 16 + l15) * 520 + kk];
        }
      } else {
        if (ks < 16) {
          int kk = ks * 32 + quad * 8;
          const u16* hbase = h1in + (size_t)t * (B_ * H_);
          af[0] = *(const bf16x8*)&hbase[(ib * 32 + l15) * 512 + kk];
          af[1] = *(const bf16x8*)&hbase[(ib * 32 + 16 + l15) * 512 + kk];
#pragma unroll
          for (int nt = 0; nt < 4; ++nt)
            bf[nt] = *(const bf16x8*)&Wib[(size_t)(nt * 512 + jn * 16 + l15) * 512 + kk];
        } else {
          int kk = (ks - 16) * 32 + quad * 8;
          af[0] = *(const bf16x8*)&Ah_s[l15 * 520 + kk];
          af[1] = *(const bf16x8*)&Ah_s[(16 + l15) * 520 + kk];
#pragma unroll
          for (int nt = 0; nt < 4; ++nt) bf[nt] = *(const bf16x8*)&Wh_s[(nt * 16 + l15) * 520 + kk];
        }
      }
#pragma unroll
      for (int mt = 0; mt < 2; ++mt)
#pragma unroll
        for (int nt = 0; nt < 4; ++nt)
          acc[mt][nt] = __builtin_amdgcn_mfma_f32_16x16x32_bf16(af[mt], bf[nt], acc[mt][nt], 0, 0, 0);
    }

    // ---- dump per-wave partials (D: col=lane&15, row=quad*4+reg) ----
#pragma unroll
    for (int mt = 0; mt < 2; ++mt)
#pragma unroll
      for (int nt = 0; nt < 4; ++nt)
#pragma unroll
        for (int r = 0; r < 4; ++r)
          Gp_s[(wv * 32 + mt * 16 + quad * 4 + r) * 68 + nt * 16 + l15] = acc[mt][nt][r];
    __syncthreads();

    // ---- elementwise: reduce partials, gates, cell/h update (1 row x 2 cols / thread) ----
    {
      float pre[4][2];
#pragma unroll
      for (int g = 0; g < 4; ++g) {
        int c = g * 16 + 2 * ecp;
        float s0 = bias2[g][0], s1 = bias2[g][1];
#pragma unroll
        for (int w = 0; w < 4; ++w) {
          s0 += Gp_s[(w * 32 + erow) * 68 + c];
          s1 += Gp_s[(w * 32 + erow) * 68 + c + 1];
        }
        pre[g][0] = s0; pre[g][1] = s1;
      }
      float hv[2];
#pragma unroll
      for (int j = 0; j < 2; ++j) {
        float iv = sigm(pre[0][j]);
        float fv = sigm(pre[1][j]);
        float gv = tanh_(pre[2][j]);
        float ov = sigm(pre[3][j]);
        float cn = fv * cst2[j] + iv * gv;
        cst2[j] = cn;
        hv[j] = ov * tanh_(cn);
      }
      int bg = ib * 32 + erow;
      int hg = jn * 16 + 2 * ecp;
      unsigned pack = (unsigned)f2b(hv[0]) | ((unsigned)f2b(hv[1]) << 16);
      size_t idx32 = (size_t)((t + 1) & 1) * (B_ * H_ / 2) + (size_t)(bg * 512 + hg) / 2;
      __hip_atomic_store(&hx32[idx32], pack, AQ, SC);  // write-through to coherence point
      if constexpr (IS_L0) {
        h1out32[((size_t)t * (B_ * H_) + (size_t)bg * 512 + hg) / 2] = pack;
      } else {
        if (t == T_ - 1) *(float2*)&h2last[bg * 512 + hg] = make_float2(hv[0], hv[1]);
      }
    }

    // ---- per-group flag barrier (32 blocks sharing batch chunk ib) ----
    if (t + 1 < T_) {
      __syncthreads();  // drains all waves' vmcnt -> h stores at coherence point
      if (tid < 64) {
        if (tid == 0) __hip_atomic_store(&flags[blockIdx.x], (unsigned)(t + 1), AQ, SC);
        unsigned* fp = &flags[ib * 32 + (tid & 31)];
        while (__hip_atomic_load(fp, AQ, SC) <= (unsigned)t) {}
      }
      __syncthreads();  // all waves wait for wave0's poll
    }
  }
}

// ---------------- final FC: out[b] = h2last[b,:] . Wfc + bfc ----------------
__global__ void fc_kernel(const float* __restrict__ h2, const float* __restrict__ Wfc,
                          const float* __restrict__ bfc, float* __restrict__ out) {
  int b = blockIdx.x, l = threadIdx.x;  // 64 threads
  float s = 0.f;
#pragma unroll
  for (int j = 0; j < 8; ++j) s += h2[b * 512 + l + j * 64] * Wfc[l + j * 64];
#pragma unroll
  for (int off = 32; off; off >>= 1) s += __shfl_down(s, off);
  if (l == 0) out[b] = s + bfc[0];
}

extern "C" void kernel_launch(void* const* d_in, const int* in_sizes, int n_in,
                              void* d_out, int out_size, void* d_ws, size_t ws_size,
                              hipStream_t stream) {
  if (ws_size < (size_t)WS_NEEDED) return;  // need ~135.3 MB scratch

  const float* x    = (const float*)d_in[0];
  const float* Wih0 = (const float*)d_in[1];
  const float* Whh0 = (const float*)d_in[2];
  const float* bih0 = (const float*)d_in[3];
  const float* bhh0 = (const float*)d_in[4];
  const float* Wih1 = (const float*)d_in[5];
  const float* Whh1 = (const float*)d_in[6];
  const float* bih1 = (const float*)d_in[7];
  const float* bhh1 = (const float*)d_in[8];
  const float* Wfc  = (const float*)d_in[9];
  const float* bfc  = (const float*)d_in[10];

  char* ws = (char*)d_ws;
  unsigned* flags = (unsigned*)(ws + OFF_FLAGS);
  float* b0      = (float*)(ws + OFF_B0);
  float* b1      = (float*)(ws + OFF_B1);
  u16* wih0b     = (u16*)(ws + OFF_WIH0);
  u16* whh0b     = (u16*)(ws + OFF_WHH0);
  u16* wih1b     = (u16*)(ws + OFF_WIH1);
  u16* whh1b     = (u16*)(ws + OFF_WHH1);
  unsigned* hx32 = (unsigned*)(ws + OFF_HX);
  float* h2l     = (float*)(ws + OFF_H2L);
  u16* h1ws      = (u16*)(ws + OFF_H1);
  float* out     = (float*)d_out;

  // prep: 512 + 2048*2 + 131072 + 3*1048576 = 3,281,408 elements = 12818 x 256
  prep_kernel<<<12818, 256, 0, stream>>>(Wih0, Whh0, bih0, bhh0, Wih1, Whh1, bih1, bhh1, ws);

  lstm_layer<true><<<256, 256, 0, stream>>>(x, wih0b, whh0b, b0, hx32, (const u16*)nullptr,
                                            (unsigned*)h1ws, (float*)nullptr, flags);
  lstm_layer<false><<<256, 256, 0, stream>>>((const float*)nullptr, wih1b, whh1b, b1, hx32,
                                             h1ws, (unsigned*)nullptr, h2l, flags + 256);
  fc_kernel<<<256, 64, 0, stream>>>(h2l, Wfc, bfc, out);
}

// Round 4
// 4568.194 us; speedup vs baseline: 5.2939x; 1.9473x over previous
//
#include <hip/hip_runtime.h>

typedef unsigned short u16;
typedef unsigned long long u64;
typedef short bf16x8 __attribute__((ext_vector_type(8)));
typedef float f32x4 __attribute__((ext_vector_type(4)));

#define B_ 256
#define T_ 512
#define I_ 64
#define H_ 512

// ---------------- ws layout (bytes) ----------------
// flags: [8 groups][32 consumers] x 128B line (32 u32 producer slots). Shared by both
// layers via monotone targets (L0: t, L1: 512+t).
#define OFF_FLAGS 0u           // 8192 u32 = 32 KB
#define OFF_B0    32768u       // 2048 f32
#define OFF_B1    40960u       // 2048 f32
#define OFF_WIH0  49152u       // 2048x64 bf16
#define OFF_WHH0  311296u      // 2048x512 bf16
#define OFF_WIH1  2408448u     // 2048x512 bf16
#define OFF_WHH1  4505600u     // 2048x512 bf16
#define OFF_HX    6602752u     // 2 x 256 x 512 bf16
#define OFF_H1    7127040u     // 512x256x512 bf16
#define WS_NEEDED 141344768u   // < 141838336 (known-good from r2/r3)

#define AQ __ATOMIC_RELAXED
#define SC __HIP_MEMORY_SCOPE_AGENT

static __device__ __forceinline__ u16 f2b(float f) {
  union { float f; unsigned u; } v; v.f = f;
  unsigned r = (v.u + 0x7FFFu + ((v.u >> 16) & 1u)) >> 16;
  return (u16)r;
}
static __device__ __forceinline__ float sigm(float x) { return 1.f / (1.f + __expf(-x)); }
static __device__ __forceinline__ float tanh_(float x) { return 1.f - 2.f / (__expf(2.f * x) + 1.f); }

// ---------------- prep: bf16 weights, bias sums, flag zero, out init ----------------
__global__ void prep_kernel(const float* __restrict__ Wih0, const float* __restrict__ Whh0,
                            const float* __restrict__ bih0, const float* __restrict__ bhh0,
                            const float* __restrict__ Wih1, const float* __restrict__ Whh1,
                            const float* __restrict__ bih1, const float* __restrict__ bhh1,
                            const float* __restrict__ bfc, float* __restrict__ out,
                            char* __restrict__ ws) {
  unsigned* flags = (unsigned*)(ws + OFF_FLAGS);
  float* b0 = (float*)(ws + OFF_B0);
  float* b1 = (float*)(ws + OFF_B1);
  u16* wih0b = (u16*)(ws + OFF_WIH0);
  u16* whh0b = (u16*)(ws + OFF_WHH0);
  u16* wih1b = (u16*)(ws + OFF_WIH1);
  u16* whh1b = (u16*)(ws + OFF_WHH1);

  long long i = (long long)blockIdx.x * 256 + threadIdx.x;
  if (i < 8192) { __hip_atomic_store(&flags[i], 0u, AQ, SC); return; }
  i -= 8192;
  if (i < 256) { out[i] = bfc[0]; return; }   // FC bias init; L1 atomicAdds partials
  i -= 256;
  if (i < 2048) { b0[i] = bih0[i] + bhh0[i]; return; }
  i -= 2048;
  if (i < 2048) { b1[i] = bih1[i] + bhh1[i]; return; }
  i -= 2048;
  if (i < 131072) { wih0b[i] = f2b(Wih0[i]); return; }
  i -= 131072;
  if (i < 1048576) { whh0b[i] = f2b(Whh0[i]); return; }
  i -= 1048576;
  if (i < 1048576) { wih1b[i] = f2b(Wih1[i]); return; }
  i -= 1048576;
  if (i < 1048576) { whh1b[i] = f2b(Whh1[i]); return; }
}

// ---------------- persistent LSTM layer ----------------
// grid = 256 blocks: jn = blockIdx&31 (16 h-cols), ib = blockIdx>>5 (32 batch rows)
// 4 waves K-split the gate GEMM (wave wv owns ksteps wv*4..wv*4+3 of 16, kstep = K:32).
// Whh (and L1 Wih) B-fragments live in VGPRs. Recurrent A-fragments load directly
// from hx with agent-scope u64 loads (no LDS staging). Mailbox: 1 polling wave per line.
template <bool IS_L0>
__global__ __launch_bounds__(256, 1) void lstm_layer(
    const float* __restrict__ x,      // L0: [B,T,64]
    const u16* __restrict__ Wib,      // bf16: L0 [2048][64], L1 [2048][512]
    const u16* __restrict__ Whb,      // bf16 [2048][512]
    const float* __restrict__ bias,   // [2048] (bih+bhh)
    unsigned* __restrict__ hx32,      // [2][256][512] bf16, u32 view (exchange)
    const u16* __restrict__ h1in,     // L1: [512][256][512] bf16
    unsigned* __restrict__ h1out32,   // L0: [512][256][512] bf16, u32 view
    const float* __restrict__ Wfc,    // L1: [512]
    float* __restrict__ out,          // L1: [256]
    unsigned* __restrict__ flags)     // [8][32][32] u32 mailbox
{
  __shared__ __align__(16) float Gp_s[4 * 32 * 68];     // per-wave gate partials
  __shared__ __align__(16) u16 Ax_s[IS_L0 ? 32 * 72 : 8];

  const int tid = threadIdx.x;
  const int wv = tid >> 6;
  const int lane = tid & 63;
  const int quad = lane >> 4;
  const int l15 = lane & 15;
  const int jn = blockIdx.x & 31;
  const int ib = blockIdx.x >> 5;
  const unsigned LBASE = IS_L0 ? 0u : 512u;

  // ---- preload B fragments into VGPRs ----
  // B-frag lane layout: n = l15 (gate col within tile nt), k = quad*8 + j
  bf16x8 Bh[4][4];
#pragma unroll
  for (int r = 0; r < 4; ++r)
#pragma unroll
    for (int nt = 0; nt < 4; ++nt)
      Bh[r][nt] = *(const bf16x8*)&Whb[(size_t)(nt * 512 + jn * 16 + l15) * 512 +
                                       (wv * 4 + r) * 32 + quad * 8];
  bf16x8 Bx[4][4];  // L1 input weights
  bf16x8 Bx0[4];    // L0 input weights (waves 0,1 only; kstep ki = wv)
  if constexpr (IS_L0) {
    if (wv < 2) {
#pragma unroll
      for (int nt = 0; nt < 4; ++nt)
        Bx0[nt] = *(const bf16x8*)&Wib[(size_t)(nt * 512 + jn * 16 + l15) * 64 +
                                       wv * 32 + quad * 8];
    }
  } else {
#pragma unroll
    for (int r = 0; r < 4; ++r)
#pragma unroll
      for (int nt = 0; nt < 4; ++nt)
        Bx[r][nt] = *(const bf16x8*)&Wib[(size_t)(nt * 512 + jn * 16 + l15) * 512 +
                                         (wv * 4 + r) * 32 + quad * 8];
  }

  // elementwise mapping: erow = batch row 0..31, ecp = col pair 0..7
  const int erow = tid >> 3;
  const int ecp = tid & 7;
  float bias2[4][2];
#pragma unroll
  for (int g = 0; g < 4; ++g) {
    bias2[g][0] = bias[g * 512 + jn * 16 + 2 * ecp];
    bias2[g][1] = bias[g * 512 + jn * 16 + 2 * ecp + 1];
  }
  float cst2[2] = {0.f, 0.f};

  const f32x4 zf = {0.f, 0.f, 0.f, 0.f};
  unsigned* myline = flags + ((unsigned)ib * 32 + jn) * 32;  // this block's poll line

  for (int t = 0; t < T_; ++t) {
    // ---- L0: stage x(t) into LDS (bf16, A-layout rows) ----
    if constexpr (IS_L0) {
      int row = tid >> 3, cc = (tid & 7) * 8;
      const float* xp = x + ((size_t)(ib * 32 + row) * T_ + t) * 64 + cc;
      float4 a = *(const float4*)xp;
      float4 b = *(const float4*)(xp + 4);
      uint4 v;
      v.x = (unsigned)f2b(a.x) | ((unsigned)f2b(a.y) << 16);
      v.y = (unsigned)f2b(a.z) | ((unsigned)f2b(a.w) << 16);
      v.z = (unsigned)f2b(b.x) | ((unsigned)f2b(b.y) << 16);
      v.w = (unsigned)f2b(b.z) | ((unsigned)f2b(b.w) << 16);
      *(uint4*)&Ax_s[row * 72 + cc] = v;
      __syncthreads();
    }

    f32x4 acc[2][4];
#pragma unroll
    for (int mt = 0; mt < 2; ++mt)
#pragma unroll
      for (int nt = 0; nt < 4; ++nt) acc[mt][nt] = zf;

    // ---- input GEMM (independent of h — before the poll) ----
    if constexpr (IS_L0) {
      if (wv < 2) {
        int kk = wv * 32 + quad * 8;
        bf16x8 a0 = *(const bf16x8*)&Ax_s[l15 * 72 + kk];
        bf16x8 a1 = *(const bf16x8*)&Ax_s[(16 + l15) * 72 + kk];
#pragma unroll
        for (int nt = 0; nt < 4; ++nt) {
          acc[0][nt] = __builtin_amdgcn_mfma_f32_16x16x32_bf16(a0, Bx0[nt], acc[0][nt], 0, 0, 0);
          acc[1][nt] = __builtin_amdgcn_mfma_f32_16x16x32_bf16(a1, Bx0[nt], acc[1][nt], 0, 0, 0);
        }
      }
    } else {
      const u16* hbase = h1in + (size_t)t * (B_ * H_);
#pragma unroll
      for (int r = 0; r < 4; ++r) {
        int kk = (wv * 4 + r) * 32 + quad * 8;
        bf16x8 a0 = *(const bf16x8*)&hbase[(ib * 32 + l15) * 512 + kk];
        bf16x8 a1 = *(const bf16x8*)&hbase[(ib * 32 + 16 + l15) * 512 + kk];
#pragma unroll
        for (int nt = 0; nt < 4; ++nt) {
          acc[0][nt] = __builtin_amdgcn_mfma_f32_16x16x32_bf16(a0, Bx[r][nt], acc[0][nt], 0, 0, 0);
          acc[1][nt] = __builtin_amdgcn_mfma_f32_16x16x32_bf16(a1, Bx[r][nt], acc[1][nt], 0, 0, 0);
        }
      }
    }

    // ---- wait for h(t): wave0 polls its private mailbox line ----
    if (t && wv == 0) {
      const unsigned tgt = LBASE + (unsigned)t;
      for (;;) {
        unsigned v = (lane < 32) ? __hip_atomic_load(&myline[lane], AQ, SC) : 0xFFFFFFFFu;
        if (!__any(v < tgt)) break;
      }
    }
    __syncthreads();

    // ---- recurrent GEMM: A direct from hx (agent u64 loads), B from VGPRs ----
    if (t) {
      u64* hq = (u64*)hx32 + (size_t)(t & 1) * (B_ * H_ / 4);
      bf16x8 af[4][2];
#pragma unroll
      for (int r = 0; r < 4; ++r) {
        int kk = (wv * 4 + r) * 32 + quad * 8;
#pragma unroll
        for (int mt = 0; mt < 2; ++mt) {
          u64* p = hq + ((ib * 32 + mt * 16 + l15) * 512 + kk) / 4;
          union { u64 q[2]; bf16x8 v; } u;
          u.q[0] = __hip_atomic_load(p, AQ, SC);
          u.q[1] = __hip_atomic_load(p + 1, AQ, SC);
          af[r][mt] = u.v;
        }
      }
#pragma unroll
      for (int r = 0; r < 4; ++r)
#pragma unroll
        for (int mt = 0; mt < 2; ++mt)
#pragma unroll
          for (int nt = 0; nt < 4; ++nt)
            acc[mt][nt] = __builtin_amdgcn_mfma_f32_16x16x32_bf16(af[r][mt], Bh[r][nt],
                                                                  acc[mt][nt], 0, 0, 0);
    }

    // ---- dump per-wave partials (D: col=lane&15, row=quad*4+reg) ----
#pragma unroll
    for (int mt = 0; mt < 2; ++mt)
#pragma unroll
      for (int nt = 0; nt < 4; ++nt)
#pragma unroll
        for (int rr = 0; rr < 4; ++rr)
          Gp_s[(wv * 32 + mt * 16 + quad * 4 + rr) * 68 + nt * 16 + l15] = acc[mt][nt][rr];
    __syncthreads();

    // ---- elementwise: reduce 4 wave-partials, gates, cell/h ----
    {
      float pre[4][2];
#pragma unroll
      for (int g = 0; g < 4; ++g) {
        int c = g * 16 + 2 * ecp;
        float s0 = bias2[g][0], s1 = bias2[g][1];
#pragma unroll
        for (int w = 0; w < 4; ++w) {
          s0 += Gp_s[(w * 32 + erow) * 68 + c];
          s1 += Gp_s[(w * 32 + erow) * 68 + c + 1];
        }
        pre[g][0] = s0; pre[g][1] = s1;
      }
      float hv[2];
#pragma unroll
      for (int j = 0; j < 2; ++j) {
        float iv = sigm(pre[0][j]);
        float fv = sigm(pre[1][j]);
        float gv = tanh_(pre[2][j]);
        float ov = sigm(pre[3][j]);
        float cn = fv * cst2[j] + iv * gv;
        cst2[j] = cn;
        hv[j] = ov * tanh_(cn);
      }
      int bg = ib * 32 + erow;
      int hg = jn * 16 + 2 * ecp;
      unsigned pack = (unsigned)f2b(hv[0]) | ((unsigned)f2b(hv[1]) << 16);
      size_t idx32 = (size_t)((t + 1) & 1) * (B_ * H_ / 2) + (size_t)(bg * 512 + hg) / 2;
      __hip_atomic_store(&hx32[idx32], pack, AQ, SC);  // write-through to coherence point
      if constexpr (IS_L0) {
        h1out32[((size_t)t * (B_ * H_) + (size_t)bg * 512 + hg) / 2] = pack;
      } else if (t == T_ - 1) {
        // fused FC: out[bg] += sum_h h2[bg,h] * Wfc[h]
        float part = hv[0] * Wfc[hg] + hv[1] * Wfc[hg + 1];
        part += __shfl_down(part, 4, 8);
        part += __shfl_down(part, 2, 8);
        part += __shfl_down(part, 1, 8);
        if (ecp == 0) atomicAdd(&out[bg], part);
      }
    }

    // ---- signal: drain stores, then scatter flag to all 32 consumers ----
    if (t + 1 < T_) {
      __syncthreads();  // emits s_waitcnt vmcnt(0) before s_barrier -> h at coherence pt
      if (wv == 0 && lane < 32)
        __hip_atomic_store(&flags[((unsigned)ib * 32 + lane) * 32 + jn],
                           LBASE + (unsigned)(t + 1), AQ, SC);
    }
  }
}

extern "C" void kernel_launch(void* const* d_in, const int* in_sizes, int n_in,
                              void* d_out, int out_size, void* d_ws, size_t ws_size,
                              hipStream_t stream) {
  if (ws_size < (size_t)WS_NEEDED) return;

  const float* x    = (const float*)d_in[0];
  const float* Wih0 = (const float*)d_in[1];
  const float* Whh0 = (const float*)d_in[2];
  const float* bih0 = (const float*)d_in[3];
  const float* bhh0 = (const float*)d_in[4];
  const float* Wih1 = (const float*)d_in[5];
  const float* Whh1 = (const float*)d_in[6];
  const float* bih1 = (const float*)d_in[7];
  const float* bhh1 = (const float*)d_in[8];
  const float* Wfc  = (const float*)d_in[9];
  const float* bfc  = (const float*)d_in[10];

  char* ws = (char*)d_ws;
  unsigned* flags = (unsigned*)(ws + OFF_FLAGS);
  float* b0      = (float*)(ws + OFF_B0);
  float* b1      = (float*)(ws + OFF_B1);
  u16* wih0b     = (u16*)(ws + OFF_WIH0);
  u16* whh0b     = (u16*)(ws + OFF_WHH0);
  u16* wih1b     = (u16*)(ws + OFF_WIH1);
  u16* whh1b     = (u16*)(ws + OFF_WHH1);
  unsigned* hx32 = (unsigned*)(ws + OFF_HX);
  u16* h1ws      = (u16*)(ws + OFF_H1);
  float* out     = (float*)d_out;

  // prep: 8192 + 256 + 2048*2 + 131072 + 3*1048576 = 3,289,920 elements
  prep_kernel<<<12852, 256, 0, stream>>>(Wih0, Whh0, bih0, bhh0, Wih1, Whh1, bih1, bhh1,
                                         bfc, out, ws);

  lstm_layer<true><<<256, 256, 0, stream>>>(x, wih0b, whh0b, b0, hx32, (const u16*)nullptr,
                                            (unsigned*)h1ws, (const float*)nullptr,
                                            (float*)nullptr, flags);
  lstm_layer<false><<<256, 256, 0, stream>>>((const float*)nullptr, wih1b, whh1b, b1, hx32,
                                             h1ws, (unsigned*)nullptr, Wfc, out, flags);
}

// Round 5
// 4174.580 us; speedup vs baseline: 5.7930x; 1.0943x over previous
//
#include <hip/hip_runtime.h>

typedef unsigned short u16;
typedef unsigned long long u64;
typedef short bf16x8 __attribute__((ext_vector_type(8)));
typedef float f32x4 __attribute__((ext_vector_type(4)));

#define B_ 256
#define T_ 512
#define I_ 64
#define H_ 512
#define RING 32

// ---------------- ws layout (bytes) ----------------
// Mailboxes: [8 groups][32 consumers] lines of 32 u32 slots (128 B, one polling wave each).
// F0: L0 recurrent; F1: L0->L1 h1-ready; F2: L1 recurrent; F3: L1->L0 h1-consumed.
#define OFF_F0    0u
#define OFF_F1    32768u
#define OFF_F2    65536u
#define OFF_F3    98304u
#define OFF_B0    131072u      // 2048 f32
#define OFF_B1    139264u      // 2048 f32
#define OFF_WIH0  147456u      // 2048x64 bf16
#define OFF_WHH0  409600u      // 2048x512 bf16
#define OFF_WIH1  2506752u     // 2048x512 bf16
#define OFF_WHH1  4603904u     // 2048x512 bf16
#define OFF_HX0   6701056u     // 2 x 256 x 512 bf16 (L0 exchange)
#define OFF_HX1   7225344u     // 2 x 256 x 512 bf16 (L1 exchange)
#define OFF_H1R   7749632u     // RING x 256 x 512 bf16 ring
#define WS_NEEDED 16138240u

#define AQ __ATOMIC_RELAXED
#define SC __HIP_MEMORY_SCOPE_AGENT

static __device__ __forceinline__ u16 f2b(float f) {
  union { float f; unsigned u; } v; v.f = f;
  unsigned r = (v.u + 0x7FFFu + ((v.u >> 16) & 1u)) >> 16;
  return (u16)r;
}
static __device__ __forceinline__ float sigm(float x) { return 1.f / (1.f + __expf(-x)); }
static __device__ __forceinline__ float tanh_(float x) { return 1.f - 2.f / (__expf(2.f * x) + 1.f); }

// ---------------- prep: bf16 weights, bias sums, flag zero, out=bfc ----------------
__global__ void prep_kernel(const float* __restrict__ Wih0, const float* __restrict__ Whh0,
                            const float* __restrict__ bih0, const float* __restrict__ bhh0,
                            const float* __restrict__ Wih1, const float* __restrict__ Whh1,
                            const float* __restrict__ bih1, const float* __restrict__ bhh1,
                            const float* __restrict__ bfc, float* __restrict__ out,
                            char* __restrict__ ws) {
  unsigned* flags = (unsigned*)(ws + OFF_F0);  // F0..F3 contiguous: 32768 u32
  float* b0 = (float*)(ws + OFF_B0);
  float* b1 = (float*)(ws + OFF_B1);
  u16* wih0b = (u16*)(ws + OFF_WIH0);
  u16* whh0b = (u16*)(ws + OFF_WHH0);
  u16* wih1b = (u16*)(ws + OFF_WIH1);
  u16* whh1b = (u16*)(ws + OFF_WHH1);

  long long i = (long long)blockIdx.x * 256 + threadIdx.x;
  if (i < 32768) { __hip_atomic_store(&flags[i], 0u, AQ, SC); return; }
  i -= 32768;
  if (i < 256) { out[i] = bfc[0]; return; }   // FC bias; L1 atomicAdds partials
  i -= 256;
  if (i < 2048) { b0[i] = bih0[i] + bhh0[i]; return; }
  i -= 2048;
  if (i < 2048) { b1[i] = bih1[i] + bhh1[i]; return; }
  i -= 2048;
  if (i < 131072) { wih0b[i] = f2b(Wih0[i]); return; }
  i -= 131072;
  if (i < 1048576) { whh0b[i] = f2b(Whh0[i]); return; }
  i -= 1048576;
  if (i < 1048576) { wih1b[i] = f2b(Wih1[i]); return; }
  i -= 1048576;
  if (i < 1048576) { whh1b[i] = f2b(Whh1[i]); return; }
}

// ---------------- fused 2-layer pipelined LSTM ----------------
// 512 blocks co-resident (2 blocks/CU): blocks 0-255 = layer0, 256-511 = layer1 (lag 1 step).
// Per layer: jn = bx&31 (16 h-cols), ib = bx>>5 (32 batch rows); 4 waves K-split; weights in VGPRs.
template <bool IS_L0>
__device__ __forceinline__ void lstm_body(
    int bx,
    const float* __restrict__ x,      // L0: [B,T,64]
    const u16* __restrict__ Wib,      // bf16: L0 [2048][64], L1 [2048][512]
    const u16* __restrict__ Whb,      // bf16 [2048][512]
    const float* __restrict__ bias,   // [2048]
    unsigned* __restrict__ hx32,      // own exchange [2][256][512] bf16, u32 view
    u16* __restrict__ h1ring,         // ring [RING][256][512] bf16
    const float* __restrict__ Wfc, float* __restrict__ out,
    unsigned* __restrict__ fR,        // own recurrent mailbox
    unsigned* __restrict__ fP,        // h1-ready mailbox (L0 produces, L1 polls)
    unsigned* __restrict__ fC,        // h1-consumed mailbox (L1 produces, L0 polls)
    float* __restrict__ Gp_s, u16* __restrict__ Ax_s)
{
  const int tid = threadIdx.x;
  const int wv = tid >> 6;
  const int lane = tid & 63;
  const int quad = lane >> 4;
  const int l15 = lane & 15;
  const int jn = bx & 31;
  const int ib = bx >> 5;

  // ---- preload B fragments into VGPRs (lane: n=l15, k=quad*8+j); wave owns ksteps wv*4..wv*4+3
  bf16x8 Bh[4][4];
#pragma unroll
  for (int r = 0; r < 4; ++r)
#pragma unroll
    for (int nt = 0; nt < 4; ++nt)
      Bh[r][nt] = *(const bf16x8*)&Whb[(size_t)(nt * 512 + jn * 16 + l15) * 512 +
                                       (wv * 4 + r) * 32 + quad * 8];
  bf16x8 Bx[4][4];  // L1 input weights (full K=512 split)
  bf16x8 Bx0[4];    // L0 input weights (waves 0,1; kstep = wv)
  if constexpr (IS_L0) {
    if (wv < 2) {
#pragma unroll
      for (int nt = 0; nt < 4; ++nt)
        Bx0[nt] = *(const bf16x8*)&Wib[(size_t)(nt * 512 + jn * 16 + l15) * 64 +
                                       wv * 32 + quad * 8];
    }
  } else {
#pragma unroll
    for (int r = 0; r < 4; ++r)
#pragma unroll
      for (int nt = 0; nt < 4; ++nt)
        Bx[r][nt] = *(const bf16x8*)&Wib[(size_t)(nt * 512 + jn * 16 + l15) * 512 +
                                         (wv * 4 + r) * 32 + quad * 8];
  }

  const int erow = tid >> 3;     // elementwise: batch row 0..31
  const int ecp = tid & 7;       // col pair
  float bias2[4][2];
#pragma unroll
  for (int g = 0; g < 4; ++g) {
    bias2[g][0] = bias[g * 512 + jn * 16 + 2 * ecp];
    bias2[g][1] = bias[g * 512 + jn * 16 + 2 * ecp + 1];
  }
  float cst2[2] = {0.f, 0.f};
  const f32x4 zf = {0.f, 0.f, 0.f, 0.f};
  const unsigned lineoff = ((unsigned)ib * 32 + jn) * 32;

  for (int t = 0; t < T_; ++t) {
    if constexpr (IS_L0) {
      // stage x(t) -> LDS (bf16 A-rows)
      int row = tid >> 3, cc = (tid & 7) * 8;
      const float* xp = x + ((size_t)(ib * 32 + row) * T_ + t) * 64 + cc;
      float4 a = *(const float4*)xp;
      float4 b = *(const float4*)(xp + 4);
      uint4 v;
      v.x = (unsigned)f2b(a.x) | ((unsigned)f2b(a.y) << 16);
      v.y = (unsigned)f2b(a.z) | ((unsigned)f2b(a.w) << 16);
      v.z = (unsigned)f2b(b.x) | ((unsigned)f2b(b.y) << 16);
      v.w = (unsigned)f2b(b.z) | ((unsigned)f2b(b.w) << 16);
      *(uint4*)&Ax_s[row * 72 + cc] = v;
      __syncthreads();
    }

    f32x4 acc[2][4];
#pragma unroll
    for (int mt = 0; mt < 2; ++mt)
#pragma unroll
      for (int nt = 0; nt < 4; ++nt) acc[mt][nt] = zf;

    if constexpr (IS_L0) {
      // input GEMM (h-independent, before poll)
      if (wv < 2) {
        int kk = wv * 32 + quad * 8;
        bf16x8 a0 = *(const bf16x8*)&Ax_s[l15 * 72 + kk];
        bf16x8 a1 = *(const bf16x8*)&Ax_s[(16 + l15) * 72 + kk];
#pragma unroll
        for (int nt = 0; nt < 4; ++nt) {
          acc[0][nt] = __builtin_amdgcn_mfma_f32_16x16x32_bf16(a0, Bx0[nt], acc[0][nt], 0, 0, 0);
          acc[1][nt] = __builtin_amdgcn_mfma_f32_16x16x32_bf16(a1, Bx0[nt], acc[1][nt], 0, 0, 0);
        }
      }
      // poll: lanes0-31 recurrent ready (fR>=t); lanes32-63 ring back-pressure (fC>=t-RING+1)
      if (t && wv == 0) {
        unsigned tgtR = (unsigned)t;
        unsigned tgtC = (t >= RING) ? (unsigned)(t - RING + 1) : 0u;
        for (;;) {
          unsigned vv, tg;
          if (lane < 32) { vv = __hip_atomic_load(&fR[lineoff + lane], AQ, SC); tg = tgtR; }
          else           { vv = __hip_atomic_load(&fC[lineoff + lane - 32], AQ, SC); tg = tgtC; }
          if (!__any(vv < tg)) break;
        }
      }
      __syncthreads();
    } else {
      // poll: lanes0-31 h1(t) ready (fP>=t+1); lanes32-63 own recurrent (fR>=t)
      if (wv == 0) {
        unsigned tgtP = (unsigned)(t + 1);
        unsigned tgtR = (unsigned)t;
        for (;;) {
          unsigned vv, tg;
          if (lane < 32) { vv = __hip_atomic_load(&fP[lineoff + lane], AQ, SC); tg = tgtP; }
          else           { vv = __hip_atomic_load(&fR[lineoff + lane - 32], AQ, SC); tg = tgtR; }
          if (!__any(vv < tg)) break;
        }
      }
      __syncthreads();
      // input GEMM from h1 ring slot t&(RING-1), agent u64 loads
      const u64* hq1 = (const u64*)h1ring + (size_t)(t & (RING - 1)) * (B_ * H_ / 4);
#pragma unroll
      for (int r = 0; r < 4; ++r) {
        int kk = (wv * 4 + r) * 32 + quad * 8;
        bf16x8 af[2];
#pragma unroll
        for (int mt = 0; mt < 2; ++mt) {
          const u64* p = hq1 + ((ib * 32 + mt * 16 + l15) * 512 + kk) / 4;
          union { u64 q[2]; bf16x8 v; } u;
          u.q[0] = __hip_atomic_load(p, AQ, SC);
          u.q[1] = __hip_atomic_load(p + 1, AQ, SC);
          af[mt] = u.v;
        }
#pragma unroll
        for (int nt = 0; nt < 4; ++nt) {
          acc[0][nt] = __builtin_amdgcn_mfma_f32_16x16x32_bf16(af[0], Bx[r][nt], acc[0][nt], 0, 0, 0);
          acc[1][nt] = __builtin_amdgcn_mfma_f32_16x16x32_bf16(af[1], Bx[r][nt], acc[1][nt], 0, 0, 0);
        }
      }
    }

    // ---- recurrent GEMM: A direct from own hx (agent u64), B resident in VGPRs
    if (t) {
      const u64* hq = (const u64*)hx32 + (size_t)(t & 1) * (B_ * H_ / 4);
      bf16x8 af[4][2];
#pragma unroll
      for (int r = 0; r < 4; ++r) {
        int kk = (wv * 4 + r) * 32 + quad * 8;
#pragma unroll
        for (int mt = 0; mt < 2; ++mt) {
          const u64* p = hq + ((ib * 32 + mt * 16 + l15) * 512 + kk) / 4;
          union { u64 q[2]; bf16x8 v; } u;
          u.q[0] = __hip_atomic_load(p, AQ, SC);
          u.q[1] = __hip_atomic_load(p + 1, AQ, SC);
          af[r][mt] = u.v;
        }
      }
#pragma unroll
      for (int r = 0; r < 4; ++r)
#pragma unroll
        for (int mt = 0; mt < 2; ++mt)
#pragma unroll
          for (int nt = 0; nt < 4; ++nt)
            acc[mt][nt] = __builtin_amdgcn_mfma_f32_16x16x32_bf16(af[r][mt], Bh[r][nt],
                                                                  acc[mt][nt], 0, 0, 0);
    }

    // ---- dump per-wave partials (D: col=l15, row=quad*4+reg)
#pragma unroll
    for (int mt = 0; mt < 2; ++mt)
#pragma unroll
      for (int nt = 0; nt < 4; ++nt)
#pragma unroll
        for (int rr = 0; rr < 4; ++rr)
          Gp_s[(wv * 32 + mt * 16 + quad * 4 + rr) * 68 + nt * 16 + l15] = acc[mt][nt][rr];
    __syncthreads();

    // ---- elementwise: reduce partials, gates, c/h update
    {
      float pre[4][2];
#pragma unroll
      for (int g = 0; g < 4; ++g) {
        int c = g * 16 + 2 * ecp;
        float s0 = bias2[g][0], s1 = bias2[g][1];
#pragma unroll
        for (int w = 0; w < 4; ++w) {
          s0 += Gp_s[(w * 32 + erow) * 68 + c];
          s1 += Gp_s[(w * 32 + erow) * 68 + c + 1];
        }
        pre[g][0] = s0; pre[g][1] = s1;
      }
      float hv[2];
#pragma unroll
      for (int j = 0; j < 2; ++j) {
        float iv = sigm(pre[0][j]);
        float fv = sigm(pre[1][j]);
        float gv = tanh_(pre[2][j]);
        float ov = sigm(pre[3][j]);
        float cn = fv * cst2[j] + iv * gv;
        cst2[j] = cn;
        hv[j] = ov * tanh_(cn);
      }
      int bg = ib * 32 + erow;
      int hg = jn * 16 + 2 * ecp;
      unsigned pack = (unsigned)f2b(hv[0]) | ((unsigned)f2b(hv[1]) << 16);
      size_t idx32 = (size_t)((t + 1) & 1) * (B_ * H_ / 2) + (size_t)(bg * 512 + hg) / 2;
      __hip_atomic_store(&hx32[idx32], pack, AQ, SC);  // write-through
      if constexpr (IS_L0) {
        unsigned* ring32 = (unsigned*)h1ring;
        __hip_atomic_store(&ring32[(size_t)(t & (RING - 1)) * (B_ * H_ / 2) +
                                   (size_t)(bg * 512 + hg) / 2], pack, AQ, SC);
      } else if (t == T_ - 1) {
        float part = hv[0] * Wfc[hg] + hv[1] * Wfc[hg + 1];
        part += __shfl_down(part, 4, 8);
        part += __shfl_down(part, 2, 8);
        part += __shfl_down(part, 1, 8);
        if (ecp == 0) atomicAdd(&out[bg], part);
      }
    }

    // ---- signal (drain h stores via syncthreads' vmcnt(0), then scatter)
    if constexpr (IS_L0) {
      __syncthreads();
      if (wv == 0) {
        unsigned val = (unsigned)(t + 1);
        if (lane < 32) {
          if (t + 1 < T_)
            __hip_atomic_store(&fR[((unsigned)ib * 32 + lane) * 32 + jn], val, AQ, SC);
        } else {
          __hip_atomic_store(&fP[((unsigned)ib * 32 + (lane - 32)) * 32 + jn], val, AQ, SC);
        }
      }
    } else {
      if (t + 1 < T_) {
        __syncthreads();
        if (wv == 0) {
          unsigned val = (unsigned)(t + 1);
          if (lane < 32)
            __hip_atomic_store(&fR[((unsigned)ib * 32 + lane) * 32 + jn], val, AQ, SC);
          else
            __hip_atomic_store(&fC[((unsigned)ib * 32 + (lane - 32)) * 32 + jn], val, AQ, SC);
        }
      }
    }
  }
}

__global__ __launch_bounds__(256, 2) void lstm_fused(
    const float* __restrict__ x,
    const u16* __restrict__ wih0, const u16* __restrict__ whh0, const float* __restrict__ b0,
    const u16* __restrict__ wih1, const u16* __restrict__ whh1, const float* __restrict__ b1,
    unsigned* __restrict__ hx0, unsigned* __restrict__ hx1, u16* __restrict__ h1ring,
    const float* __restrict__ Wfc, float* __restrict__ out,
    unsigned* __restrict__ f0, unsigned* __restrict__ f1, unsigned* __restrict__ f2,
    unsigned* __restrict__ f3)
{
  __shared__ __align__(16) float Gp_s[4 * 32 * 68];
  __shared__ __align__(16) u16 Ax_s[32 * 72];
  if (blockIdx.x < 256)
    lstm_body<true>(blockIdx.x, x, wih0, whh0, b0, hx0, h1ring,
                    (const float*)nullptr, (float*)nullptr, f0, f1, f3, Gp_s, Ax_s);
  else
    lstm_body<false>(blockIdx.x - 256, (const float*)nullptr, wih1, whh1, b1, hx1, h1ring,
                     Wfc, out, f2, f1, f3, Gp_s, Ax_s);
}

extern "C" void kernel_launch(void* const* d_in, const int* in_sizes, int n_in,
                              void* d_out, int out_size, void* d_ws, size_t ws_size,
                              hipStream_t stream) {
  if (ws_size < (size_t)WS_NEEDED) return;

  const float* x    = (const float*)d_in[0];
  const float* Wih0 = (const float*)d_in[1];
  const float* Whh0 = (const float*)d_in[2];
  const float* bih0 = (const float*)d_in[3];
  const float* bhh0 = (const float*)d_in[4];
  const float* Wih1 = (const float*)d_in[5];
  const float* Whh1 = (const float*)d_in[6];
  const float* bih1 = (const float*)d_in[7];
  const float* bhh1 = (const float*)d_in[8];
  const float* Wfc  = (const float*)d_in[9];
  const float* bfc  = (const float*)d_in[10];

  char* ws = (char*)d_ws;
  unsigned* f0   = (unsigned*)(ws + OFF_F0);
  unsigned* f1   = (unsigned*)(ws + OFF_F1);
  unsigned* f2   = (unsigned*)(ws + OFF_F2);
  unsigned* f3   = (unsigned*)(ws + OFF_F3);
  float* b0      = (float*)(ws + OFF_B0);
  float* b1      = (float*)(ws + OFF_B1);
  u16* wih0b     = (u16*)(ws + OFF_WIH0);
  u16* whh0b     = (u16*)(ws + OFF_WHH0);
  u16* wih1b     = (u16*)(ws + OFF_WIH1);
  u16* whh1b     = (u16*)(ws + OFF_WHH1);
  unsigned* hx0  = (unsigned*)(ws + OFF_HX0);
  unsigned* hx1  = (unsigned*)(ws + OFF_HX1);
  u16* h1ring    = (u16*)(ws + OFF_H1R);
  float* out     = (float*)d_out;

  // prep: 32768 + 256 + 2048*2 + 131072 + 3*1048576 = 3,314,560 elements
  prep_kernel<<<12948, 256, 0, stream>>>(Wih0, Whh0, bih0, bhh0, Wih1, Whh1, bih1, bhh1,
                                         bfc, out, ws);

  lstm_fused<<<512, 256, 0, stream>>>(x, wih0b, whh0b, b0, wih1b, whh1b, b1,
                                      hx0, hx1, h1ring, Wfc, out, f0, f1, f2, f3);
}

// Round 6
// 2943.286 us; speedup vs baseline: 8.2165x; 1.4183x over previous
//
#include <hip/hip_runtime.h>

typedef unsigned short u16;
typedef unsigned long long u64;
typedef short bf16x8 __attribute__((ext_vector_type(8)));
typedef float f32x4 __attribute__((ext_vector_type(4)));

#define B_ 256
#define T_ 512
#define I_ 64
#define H_ 512
#define RING 32

// ---------------- ws layout (bytes) ----------------
// Mailboxes: [8 groups][32 consumers] lines of 32 u32 slots (128 B, one polling wave each).
// F0: L0 recurrent; F1: L0->L1 h1-ready; F2: L1 recurrent; F3: L1->L0 h1-consumed.
// hx / ring layout is A-FRAGMENT-COALESCED: [k8 = k/8][row 0..255][8 k-elems] bf16,
// so consumer lane (l15,quad) loads 16B contiguous and 16 lanes cover 256B/quad.
#define OFF_F0    0u
#define OFF_F1    32768u
#define OFF_F2    65536u
#define OFF_F3    98304u
#define OFF_B0    131072u      // 2048 f32
#define OFF_B1    139264u      // 2048 f32
#define OFF_WIH0  147456u      // 2048x64 bf16
#define OFF_WHH0  409600u      // 2048x512 bf16
#define OFF_WIH1  2506752u     // 2048x512 bf16
#define OFF_WHH1  4603904u     // 2048x512 bf16
#define OFF_HX0   6701056u     // 2 x [64][256][8] bf16 (L0 exchange, transposed)
#define OFF_HX1   7225344u     // 2 x [64][256][8] bf16 (L1 exchange, transposed)
#define OFF_H1R   7749632u     // RING x [64][256][8] bf16 ring (transposed)
#define WS_NEEDED 16138240u

#define AQ __ATOMIC_RELAXED
#define SC __HIP_MEMORY_SCOPE_AGENT

static __device__ __forceinline__ u16 f2b(float f) {
  union { float f; unsigned u; } v; v.f = f;
  unsigned r = (v.u + 0x7FFFu + ((v.u >> 16) & 1u)) >> 16;
  return (u16)r;
}
static __device__ __forceinline__ float sigm(float x) { return 1.f / (1.f + __expf(-x)); }
static __device__ __forceinline__ float tanh_(float x) { return 1.f - 2.f / (__expf(2.f * x) + 1.f); }

// ---------------- prep: bf16 weights, bias sums, flag zero, out=bfc ----------------
__global__ void prep_kernel(const float* __restrict__ Wih0, const float* __restrict__ Whh0,
                            const float* __restrict__ bih0, const float* __restrict__ bhh0,
                            const float* __restrict__ Wih1, const float* __restrict__ Whh1,
                            const float* __restrict__ bih1, const float* __restrict__ bhh1,
                            const float* __restrict__ bfc, float* __restrict__ out,
                            char* __restrict__ ws) {
  unsigned* flags = (unsigned*)(ws + OFF_F0);  // F0..F3 contiguous: 32768 u32
  float* b0 = (float*)(ws + OFF_B0);
  float* b1 = (float*)(ws + OFF_B1);
  u16* wih0b = (u16*)(ws + OFF_WIH0);
  u16* whh0b = (u16*)(ws + OFF_WHH0);
  u16* wih1b = (u16*)(ws + OFF_WIH1);
  u16* whh1b = (u16*)(ws + OFF_WHH1);

  long long i = (long long)blockIdx.x * 256 + threadIdx.x;
  if (i < 32768) { __hip_atomic_store(&flags[i], 0u, AQ, SC); return; }
  i -= 32768;
  if (i < 256) { out[i] = bfc[0]; return; }   // FC bias; L1 atomicAdds partials
  i -= 256;
  if (i < 2048) { b0[i] = bih0[i] + bhh0[i]; return; }
  i -= 2048;
  if (i < 2048) { b1[i] = bih1[i] + bhh1[i]; return; }
  i -= 2048;
  if (i < 131072) { wih0b[i] = f2b(Wih0[i]); return; }
  i -= 131072;
  if (i < 1048576) { whh0b[i] = f2b(Whh0[i]); return; }
  i -= 1048576;
  if (i < 1048576) { wih1b[i] = f2b(Wih1[i]); return; }
  i -= 1048576;
  if (i < 1048576) { whh1b[i] = f2b(Whh1[i]); return; }
}

// ---------------- fused 2-layer pipelined LSTM ----------------
// 512 blocks co-resident (2 blocks/CU): blocks 0-255 = layer0, 256-511 = layer1 (lag 1 step).
// Per layer: jn = bx&31 (16 h-cols), ib = bx>>5 (32 batch rows); 4 waves K-split; weights in VGPRs.
template <bool IS_L0>
__device__ __forceinline__ void lstm_body(
    int bx,
    const float* __restrict__ x,      // L0: [B,T,64]
    const u16* __restrict__ Wib,      // bf16: L0 [2048][64], L1 [2048][512]
    const u16* __restrict__ Whb,      // bf16 [2048][512]
    const float* __restrict__ bias,   // [2048]
    unsigned* __restrict__ hx32,      // own exchange, transposed [2][64][256][8] bf16, u32 view
    u16* __restrict__ h1ring,         // ring [RING][64][256][8] bf16 (transposed)
    const float* __restrict__ Wfc, float* __restrict__ out,
    unsigned* __restrict__ fR,        // own recurrent mailbox
    unsigned* __restrict__ fP,        // h1-ready mailbox (L0 produces, L1 polls)
    unsigned* __restrict__ fC,        // h1-consumed mailbox (L1 produces, L0 polls)
    float* __restrict__ Gp_s, u16* __restrict__ Ax_s)
{
  const int tid = threadIdx.x;
  const int wv = tid >> 6;
  const int lane = tid & 63;
  const int quad = lane >> 4;
  const int l15 = lane & 15;
  const int jn = bx & 31;
  const int ib = bx >> 5;

  // ---- preload B fragments into VGPRs (lane: n=l15, k=quad*8+j); wave owns ksteps wv*4..wv*4+3
  bf16x8 Bh[4][4];
#pragma unroll
  for (int r = 0; r < 4; ++r)
#pragma unroll
    for (int nt = 0; nt < 4; ++nt)
      Bh[r][nt] = *(const bf16x8*)&Whb[(size_t)(nt * 512 + jn * 16 + l15) * 512 +
                                       (wv * 4 + r) * 32 + quad * 8];
  bf16x8 Bx[4][4];  // L1 input weights (full K=512 split)
  bf16x8 Bx0[4];    // L0 input weights (waves 0,1; kstep = wv)
  if constexpr (IS_L0) {
    if (wv < 2) {
#pragma unroll
      for (int nt = 0; nt < 4; ++nt)
        Bx0[nt] = *(const bf16x8*)&Wib[(size_t)(nt * 512 + jn * 16 + l15) * 64 +
                                       wv * 32 + quad * 8];
    }
  } else {
#pragma unroll
    for (int r = 0; r < 4; ++r)
#pragma unroll
      for (int nt = 0; nt < 4; ++nt)
        Bx[r][nt] = *(const bf16x8*)&Wib[(size_t)(nt * 512 + jn * 16 + l15) * 512 +
                                         (wv * 4 + r) * 32 + quad * 8];
  }

  const int erow = tid >> 3;     // elementwise: batch row 0..31
  const int ecp = tid & 7;       // col pair
  float bias2[4][2];
#pragma unroll
  for (int g = 0; g < 4; ++g) {
    bias2[g][0] = bias[g * 512 + jn * 16 + 2 * ecp];
    bias2[g][1] = bias[g * 512 + jn * 16 + 2 * ecp + 1];
  }
  float cst2[2] = {0.f, 0.f};
  const f32x4 zf = {0.f, 0.f, 0.f, 0.f};
  const unsigned lineoff = ((unsigned)ib * 32 + jn) * 32;

  // transposed-layout store offset for this thread's (bg, hg) pair (u32 units):
  // hg = jn*16+2ecp -> k8 = hg>>3 = jn*2+(ecp>>2), elem pair = ecp&3
  const int bg = ib * 32 + erow;
  const int hg = jn * 16 + 2 * ecp;
  const unsigned stoff = (unsigned)(((hg >> 3) * 256 + bg) * 4 + (ecp & 3));

  for (int t = 0; t < T_; ++t) {
    if constexpr (IS_L0) {
      // stage x(t) -> LDS (bf16 A-rows)
      int row = tid >> 3, cc = (tid & 7) * 8;
      const float* xp = x + ((size_t)(ib * 32 + row) * T_ + t) * 64 + cc;
      float4 a = *(const float4*)xp;
      float4 b = *(const float4*)(xp + 4);
      uint4 v;
      v.x = (unsigned)f2b(a.x) | ((unsigned)f2b(a.y) << 16);
      v.y = (unsigned)f2b(a.z) | ((unsigned)f2b(a.w) << 16);
      v.z = (unsigned)f2b(b.x) | ((unsigned)f2b(b.y) << 16);
      v.w = (unsigned)f2b(b.z) | ((unsigned)f2b(b.w) << 16);
      *(uint4*)&Ax_s[row * 72 + cc] = v;
      __syncthreads();
    }

    f32x4 acc[2][4];
#pragma unroll
    for (int mt = 0; mt < 2; ++mt)
#pragma unroll
      for (int nt = 0; nt < 4; ++nt) acc[mt][nt] = zf;

    if constexpr (IS_L0) {
      // input GEMM (h-independent, before poll)
      if (wv < 2) {
        int kk = wv * 32 + quad * 8;
        bf16x8 a0 = *(const bf16x8*)&Ax_s[l15 * 72 + kk];
        bf16x8 a1 = *(const bf16x8*)&Ax_s[(16 + l15) * 72 + kk];
#pragma unroll
        for (int nt = 0; nt < 4; ++nt) {
          acc[0][nt] = __builtin_amdgcn_mfma_f32_16x16x32_bf16(a0, Bx0[nt], acc[0][nt], 0, 0, 0);
          acc[1][nt] = __builtin_amdgcn_mfma_f32_16x16x32_bf16(a1, Bx0[nt], acc[1][nt], 0, 0, 0);
        }
      }
      // poll: lanes0-31 recurrent ready (fR>=t); lanes32-63 ring back-pressure (fC>=t-RING+1)
      if (t && wv == 0) {
        unsigned tgtR = (unsigned)t;
        unsigned tgtC = (t >= RING) ? (unsigned)(t - RING + 1) : 0u;
        for (;;) {
          unsigned vv, tg;
          if (lane < 32) { vv = __hip_atomic_load(&fR[lineoff + lane], AQ, SC); tg = tgtR; }
          else           { vv = __hip_atomic_load(&fC[lineoff + lane - 32], AQ, SC); tg = tgtC; }
          if (!__any(vv < tg)) break;
        }
      }
      __syncthreads();
    } else {
      // poll: lanes0-31 h1(t) ready (fP>=t+1); lanes32-63 own recurrent (fR>=t)
      if (wv == 0) {
        unsigned tgtP = (unsigned)(t + 1);
        unsigned tgtR = (unsigned)t;
        for (;;) {
          unsigned vv, tg;
          if (lane < 32) { vv = __hip_atomic_load(&fP[lineoff + lane], AQ, SC); tg = tgtP; }
          else           { vv = __hip_atomic_load(&fR[lineoff + lane - 32], AQ, SC); tg = tgtR; }
          if (!__any(vv < tg)) break;
        }
      }
      __syncthreads();
      // input GEMM from h1 ring slot t&(RING-1); transposed layout -> coalesced 16B/lane
      const u64* hq1 = (const u64*)h1ring + (size_t)(t & (RING - 1)) * (B_ * H_ / 4);
#pragma unroll
      for (int r = 0; r < 4; ++r) {
        int ks = wv * 4 + r;
        bf16x8 af[2];
#pragma unroll
        for (int mt = 0; mt < 2; ++mt) {
          const u64* p = hq1 + (size_t)((ks * 4 + quad) * 256 + ib * 32 + mt * 16 + l15) * 2;
          union { u64 q[2]; bf16x8 v; } u;
          u.q[0] = __hip_atomic_load(p, AQ, SC);
          u.q[1] = __hip_atomic_load(p + 1, AQ, SC);
          af[mt] = u.v;
        }
#pragma unroll
        for (int nt = 0; nt < 4; ++nt) {
          acc[0][nt] = __builtin_amdgcn_mfma_f32_16x16x32_bf16(af[0], Bx[r][nt], acc[0][nt], 0, 0, 0);
          acc[1][nt] = __builtin_amdgcn_mfma_f32_16x16x32_bf16(af[1], Bx[r][nt], acc[1][nt], 0, 0, 0);
        }
      }
    }

    // ---- recurrent GEMM: A direct from own hx (transposed, coalesced), B in VGPRs
    if (t) {
      const u64* hq = (const u64*)hx32 + (size_t)(t & 1) * (B_ * H_ / 4);
      bf16x8 af[4][2];
#pragma unroll
      for (int r = 0; r < 4; ++r) {
        int ks = wv * 4 + r;
#pragma unroll
        for (int mt = 0; mt < 2; ++mt) {
          const u64* p = hq + (size_t)((ks * 4 + quad) * 256 + ib * 32 + mt * 16 + l15) * 2;
          union { u64 q[2]; bf16x8 v; } u;
          u.q[0] = __hip_atomic_load(p, AQ, SC);
          u.q[1] = __hip_atomic_load(p + 1, AQ, SC);
          af[r][mt] = u.v;
        }
      }
#pragma unroll
      for (int r = 0; r < 4; ++r)
#pragma unroll
        for (int mt = 0; mt < 2; ++mt)
#pragma unroll
          for (int nt = 0; nt < 4; ++nt)
            acc[mt][nt] = __builtin_amdgcn_mfma_f32_16x16x32_bf16(af[r][mt], Bh[r][nt],
                                                                  acc[mt][nt], 0, 0, 0);
    }

    // ---- dump per-wave partials (D: col=l15, row=quad*4+reg)
#pragma unroll
    for (int mt = 0; mt < 2; ++mt)
#pragma unroll
      for (int nt = 0; nt < 4; ++nt)
#pragma unroll
        for (int rr = 0; rr < 4; ++rr)
          Gp_s[(wv * 32 + mt * 16 + quad * 4 + rr) * 68 + nt * 16 + l15] = acc[mt][nt][rr];
    __syncthreads();

    // ---- elementwise: reduce partials, gates, c/h update
    {
      float pre[4][2];
#pragma unroll
      for (int g = 0; g < 4; ++g) {
        int c = g * 16 + 2 * ecp;
        float s0 = bias2[g][0], s1 = bias2[g][1];
#pragma unroll
        for (int w = 0; w < 4; ++w) {
          s0 += Gp_s[(w * 32 + erow) * 68 + c];
          s1 += Gp_s[(w * 32 + erow) * 68 + c + 1];
        }
        pre[g][0] = s0; pre[g][1] = s1;
      }
      float hv[2];
#pragma unroll
      for (int j = 0; j < 2; ++j) {
        float iv = sigm(pre[0][j]);
        float fv = sigm(pre[1][j]);
        float gv = tanh_(pre[2][j]);
        float ov = sigm(pre[3][j]);
        float cn = fv * cst2[j] + iv * gv;
        cst2[j] = cn;
        hv[j] = ov * tanh_(cn);
      }
      unsigned pack = (unsigned)f2b(hv[0]) | ((unsigned)f2b(hv[1]) << 16);
      // transposed store: per wave these form contiguous 128B lines
      __hip_atomic_store(&hx32[(size_t)((t + 1) & 1) * (B_ * H_ / 2) + stoff], pack, AQ, SC);
      if constexpr (IS_L0) {
        unsigned* ring32 = (unsigned*)h1ring;
        __hip_atomic_store(&ring32[(size_t)(t & (RING - 1)) * (B_ * H_ / 2) + stoff],
                           pack, AQ, SC);
      } else if (t == T_ - 1) {
        float part = hv[0] * Wfc[hg] + hv[1] * Wfc[hg + 1];
        part += __shfl_down(part, 4, 8);
        part += __shfl_down(part, 2, 8);
        part += __shfl_down(part, 1, 8);
        if (ecp == 0) atomicAdd(&out[bg], part);
      }
    }

    // ---- signal (drain h stores via syncthreads' vmcnt(0), then scatter)
    if constexpr (IS_L0) {
      __syncthreads();
      if (wv == 0) {
        unsigned val = (unsigned)(t + 1);
        if (lane < 32) {
          if (t + 1 < T_)
            __hip_atomic_store(&fR[((unsigned)ib * 32 + lane) * 32 + jn], val, AQ, SC);
        } else {
          __hip_atomic_store(&fP[((unsigned)ib * 32 + (lane - 32)) * 32 + jn], val, AQ, SC);
        }
      }
    } else {
      if (t + 1 < T_) {
        __syncthreads();
        if (wv == 0) {
          unsigned val = (unsigned)(t + 1);
          if (lane < 32)
            __hip_atomic_store(&fR[((unsigned)ib * 32 + lane) * 32 + jn], val, AQ, SC);
          else
            __hip_atomic_store(&fC[((unsigned)ib * 32 + (lane - 32)) * 32 + jn], val, AQ, SC);
        }
      }
    }
  }
}

__global__ __launch_bounds__(256, 2) void lstm_fused(
    const float* __restrict__ x,
    const u16* __restrict__ wih0, const u16* __restrict__ whh0, const float* __restrict__ b0,
    const u16* __restrict__ wih1, const u16* __restrict__ whh1, const float* __restrict__ b1,
    unsigned* __restrict__ hx0, unsigned* __restrict__ hx1, u16* __restrict__ h1ring,
    const float* __restrict__ Wfc, float* __restrict__ out,
    unsigned* __restrict__ f0, unsigned* __restrict__ f1, unsigned* __restrict__ f2,
    unsigned* __restrict__ f3)
{
  __shared__ __align__(16) float Gp_s[4 * 32 * 68];
  __shared__ __align__(16) u16 Ax_s[32 * 72];
  if (blockIdx.x < 256)
    lstm_body<true>(blockIdx.x, x, wih0, whh0, b0, hx0, h1ring,
                    (const float*)nullptr, (float*)nullptr, f0, f1, f3, Gp_s, Ax_s);
  else
    lstm_body<false>(blockIdx.x - 256, (const float*)nullptr, wih1, whh1, b1, hx1, h1ring,
                     Wfc, out, f2, f1, f3, Gp_s, Ax_s);
}

extern "C" void kernel_launch(void* const* d_in, const int* in_sizes, int n_in,
                              void* d_out, int out_size, void* d_ws, size_t ws_size,
                              hipStream_t stream) {
  if (ws_size < (size_t)WS_NEEDED) return;

  const float* x    = (const float*)d_in[0];
  const float* Wih0 = (const float*)d_in[1];
  const float* Whh0 = (const float*)d_in[2];
  const float* bih0 = (const float*)d_in[3];
  const float* bhh0 = (const float*)d_in[4];
  const float* Wih1 = (const float*)d_in[5];
  const float* Whh1 = (const float*)d_in[6];
  const float* bih1 = (const float*)d_in[7];
  const float* bhh1 = (const float*)d_in[8];
  const float* Wfc  = (const float*)d_in[9];
  const float* bfc  = (const float*)d_in[10];

  char* ws = (char*)d_ws;
  unsigned* f0   = (unsigned*)(ws + OFF_F0);
  unsigned* f1   = (unsigned*)(ws + OFF_F1);
  unsigned* f2   = (unsigned*)(ws + OFF_F2);
  unsigned* f3   = (unsigned*)(ws + OFF_F3);
  float* b0      = (float*)(ws + OFF_B0);
  float* b1      = (float*)(ws + OFF_B1);
  u16* wih0b     = (u16*)(ws + OFF_WIH0);
  u16* whh0b     = (u16*)(ws + OFF_WHH0);
  u16* wih1b     = (u16*)(ws + OFF_WIH1);
  u16* whh1b     = (u16*)(ws + OFF_WHH1);
  unsigned* hx0  = (unsigned*)(ws + OFF_HX0);
  unsigned* hx1  = (unsigned*)(ws + OFF_HX1);
  u16* h1ring    = (u16*)(ws + OFF_H1R);
  float* out     = (float*)d_out;

  // prep: 32768 + 256 + 2048*2 + 131072 + 3*1048576 = 3,314,560 elements
  prep_kernel<<<12948, 256, 0, stream>>>(Wih0, Whh0, bih0, bhh0, Wih1, Whh1, bih1, bhh1,
                                         bfc, out, ws);

  lstm_fused<<<512, 256, 0, stream>>>(x, wih0b, whh0b, b0, wih1b, whh1b, b1,
                                      hx0, hx1, h1ring, Wfc, out, f0, f1, f2, f3);
}